// Round 27
// baseline (97.800 us; speedup 1.0000x reference)
//
#include <hip/hip_runtime.h>
#include <math.h>

namespace {
constexpr int kB = 64;        // batch
constexpr int kN = 512;       // max_sent_num
constexpr int kD = 768;       // hidden
constexpr int kD4 = kD / 4;   // float4 per row = 192
constexpr int kS = 8;         // N-chunks for masked reduction
constexpr int kChunk = kN / kS;  // 64 rows per chunk
constexpr float kEps = 1e-5f;
}

// Module-scope device scratch: allocated at .so load (not hipMalloc), so graph
// capture never sees an allocation. Fully rewritten every call -> deterministic.
__device__ float g_part[kB * kS * kD];  // 1.5 MB
__device__ float g_t1a[kB * kD];
__device__ float g_t2a[kB * kD];
__device__ float g_t2i[kD];

// ---------------------------------------------------------------------------
// K1: partial masked reduction over N.
// g_part[(b*kS+s), d] = sum over chunk s of mask[b,n]*sent[b,n,d].
// mask==0 rows are skipped entirely (block-uniform branch -> row not fetched).
// ---------------------------------------------------------------------------
__global__ __launch_bounds__(192) void k1_partial(
    const float* __restrict__ sent, const int* __restrict__ mask) {
  int b = blockIdx.x / kS;
  int s = blockIdx.x - b * kS;
  int t = threadIdx.x;  // 0..191, one float4 column each
  __shared__ int m[kChunk];
  int n0 = s * kChunk;
  if (t < kChunk) m[t] = mask[b * kN + n0 + t];  // one coalesced mask pass
  __syncthreads();
  const float4* srow = (const float4*)(sent + (size_t)b * kN * kD);
  float4 acc = make_float4(0.f, 0.f, 0.f, 0.f);
  for (int i = 0; i < kChunk; ++i) {
    if (m[i]) {  // block-uniform
      float4 v = srow[(size_t)(n0 + i) * kD4 + t];
      acc.x += v.x; acc.y += v.y; acc.z += v.z; acc.w += v.w;
    }
  }
  ((float4*)g_part)[(size_t)(b * kS + s) * kD4 + t] = acc;
}

// ---------------------------------------------------------------------------
// K2: finish s1 reduction into LDS, then t1a[b,d]=tanh(dot(s1,W1[:,d])+b1[d]).
// grid (kB, 4): each block covers 192 consecutive d-columns.
// ---------------------------------------------------------------------------
__global__ __launch_bounds__(192) void k2_gemm1(
    const float* __restrict__ W1, const float* __restrict__ b1) {
  int b = blockIdx.x;
  int t = threadIdx.x;
  __shared__ float s1[kD];
  const float4* p4 = (const float4*)g_part;
  float4 acc = make_float4(0.f, 0.f, 0.f, 0.f);
  for (int s = 0; s < kS; ++s) {
    float4 v = p4[(size_t)(b * kS + s) * kD4 + t];
    acc.x += v.x; acc.y += v.y; acc.z += v.z; acc.w += v.w;
  }
  ((float4*)s1)[t] = acc;
  __syncthreads();
  int d = blockIdx.y * 192 + t;
  float o = 0.f;
  for (int k = 0; k < kD; ++k)
    o += s1[k] * W1[(size_t)k * kD + d];  // s1[k] LDS broadcast, W1 coalesced
  g_t1a[(size_t)b * kD + d] = tanhf(o + b1[d]);
}

// ---------------------------------------------------------------------------
// K3: cnt[b]=sum(mask[b,:]); t2a[b,d]=tanh(cnt*dot(t1a[b,:],W2[:,d])+b2[d]);
//     t2i[d]=tanh(b2[d])  (row every inactive node gets).
// ---------------------------------------------------------------------------
__global__ __launch_bounds__(192) void k3_gemm2(
    const int* __restrict__ mask, const float* __restrict__ W2,
    const float* __restrict__ b2) {
  int b = blockIdx.x;
  int t = threadIdx.x;
  __shared__ float h[kD];
  __shared__ float red[3];
  ((float4*)h)[t] = ((const float4*)g_t1a)[(size_t)b * kD4 + t];
  // wave-parallel mask count: 3 waves * 64 lanes
  float c = 0.f;
  for (int n = t; n < kN; n += 192) c += (float)mask[b * kN + n];
#pragma unroll
  for (int off = 32; off; off >>= 1) c += __shfl_xor(c, off);
  if ((t & 63) == 0) red[t >> 6] = c;
  __syncthreads();
  float cnt = red[0] + red[1] + red[2];
  int d = blockIdx.y * 192 + t;
  float o = 0.f;
  for (int k = 0; k < kD; ++k)
    o += h[k] * W2[(size_t)k * kD + d];
  g_t2a[(size_t)b * kD + d] = tanhf(cnt * o + b2[d]);
  if (b == 0) g_t2i[d] = tanhf(b2[d]);
}

// ---------------------------------------------------------------------------
// K4: out[b,n,:] = LayerNorm(sent[b,n,:] + (mask[b,n] ? t2a[b,:] : t2i[:])).
// One wave per row; 3 float4 per lane; shfl_xor reduction.
// ---------------------------------------------------------------------------
__global__ __launch_bounds__(256) void k4_fuse_ln(
    const float* __restrict__ sent, const int* __restrict__ mask,
    const float* __restrict__ gamma, const float* __restrict__ beta,
    float* __restrict__ out) {
  int wave = threadIdx.x >> 6;
  int lane = threadIdx.x & 63;
  int row = blockIdx.x * 4 + wave;      // [0, kB*kN)
  int b = row >> 9;                     // kN = 512
  int n = row & (kN - 1);
  const float4* s4 = (const float4*)(sent + (size_t)row * kD);
  const float4* a4 = mask[b * kN + n] ? (const float4*)(g_t2a + (size_t)b * kD)
                                      : (const float4*)g_t2i;
  float4 x[3], g[3], bt[3];
  float sum = 0.f, sq = 0.f;
#pragma unroll
  for (int j = 0; j < 3; ++j) {
    int idx = lane + j * 64;
    float4 sv = s4[idx];
    float4 av = a4[idx];
    g[j] = ((const float4*)gamma)[idx];   // issued early: latency overlaps reduce
    bt[j] = ((const float4*)beta)[idx];
    float4 xv = make_float4(sv.x + av.x, sv.y + av.y, sv.z + av.z, sv.w + av.w);
    x[j] = xv;
    sum += xv.x + xv.y + xv.z + xv.w;
    sq += xv.x * xv.x + xv.y * xv.y + xv.z * xv.z + xv.w * xv.w;
  }
#pragma unroll
  for (int off = 32; off; off >>= 1) {
    sum += __shfl_xor(sum, off);
    sq += __shfl_xor(sq, off);
  }
  const float inv = 1.f / (float)kD;
  float mu = sum * inv;
  float var = sq * inv - mu * mu;
  float rstd = rsqrtf(var + kEps);
  float4* o4 = (float4*)(out + (size_t)row * kD);
#pragma unroll
  for (int j = 0; j < 3; ++j) {
    int idx = lane + j * 64;
    float4 xv = x[j];
    o4[idx] = make_float4((xv.x - mu) * rstd * g[j].x + bt[j].x,
                          (xv.y - mu) * rstd * g[j].y + bt[j].y,
                          (xv.z - mu) * rstd * g[j].z + bt[j].z,
                          (xv.w - mu) * rstd * g[j].w + bt[j].w);
  }
}

extern "C" void kernel_launch(void* const* d_in, const int* in_sizes, int n_in,
                              void* d_out, int out_size, void* d_ws, size_t ws_size,
                              hipStream_t stream) {
  const float* sent  = (const float*)d_in[0];
  const int*   mask  = (const int*)d_in[1];
  const float* W1    = (const float*)d_in[2];
  const float* b1    = (const float*)d_in[3];
  const float* W2    = (const float*)d_in[4];
  const float* b2    = (const float*)d_in[5];
  const float* gamma = (const float*)d_in[6];
  const float* beta  = (const float*)d_in[7];
  float* out = (float*)d_out;
  (void)in_sizes; (void)n_in; (void)out_size; (void)d_ws; (void)ws_size;

  k1_partial<<<dim3(kB * kS), dim3(192), 0, stream>>>(sent, mask);
  k2_gemm1<<<dim3(kB, 4), dim3(192), 0, stream>>>(W1, b1);
  k3_gemm2<<<dim3(kB, 4), dim3(192), 0, stream>>>(mask, W2, b2);
  k4_fuse_ln<<<dim3((kB * kN) / 4), dim3(256), 0, stream>>>(
      sent, mask, gamma, beta, out);
}